// Round 1
// baseline (333.887 us; speedup 1.0000x reference)
//
#include <hip/hip_runtime.h>

// SoftPhongNormalShader: phong normal interpolation + softmax_rgb_blend.
// One thread per pixel (N*H*W = 1,048,576), K=8 fragments unrolled in regs.
// Memory-bound: ~218 MB of one-touch HBM traffic; faces/vn tables are
// L2-resident gathers.

#define KFRAG 8
#define SIGMA_INV 10000.0f     // 1/1e-4
#define GAMMA_INV 10000.0f     // 1/1e-4
#define ZFAR 100.0f
#define ZNER 1.0f
#define ZRANGE_INV (1.0f / 99.0f)
#define EPSV 1e-10f

__global__ __launch_bounds__(256) void soft_phong_kernel(
    const float* __restrict__ vn,     // [V,3]
    const float* __restrict__ bary,   // [P,K,3]
    const float* __restrict__ zbuf,   // [P,K]
    const float* __restrict__ dists,  // [P,K]
    const int*   __restrict__ faces,  // [F,3]
    const int*   __restrict__ p2f,    // [P,K]
    float*       __restrict__ out,    // [P,4]
    int P)
{
    int p = blockIdx.x * blockDim.x + threadIdx.x;
    if (p >= P) return;

    // ---- vectorized streaming loads (contiguous per pixel) ----
    const int4* pf4 = (const int4*)(p2f + (size_t)p * KFRAG);
    int4 fa = pf4[0], fb = pf4[1];
    int fk[KFRAG] = {fa.x, fa.y, fa.z, fa.w, fb.x, fb.y, fb.z, fb.w};

    const float4* z4 = (const float4*)(zbuf + (size_t)p * KFRAG);
    float4 za = z4[0], zb = z4[1];
    float zk[KFRAG] = {za.x, za.y, za.z, za.w, zb.x, zb.y, zb.z, zb.w};

    const float4* dd4 = (const float4*)(dists + (size_t)p * KFRAG);
    float4 da = dd4[0], db = dd4[1];
    float dk[KFRAG] = {da.x, da.y, da.z, da.w, db.x, db.y, db.z, db.w};

    const float4* b4 = (const float4*)(bary + (size_t)p * KFRAG * 3);
    float bf[24];
    #pragma unroll
    for (int j = 0; j < 6; j++) {
        float4 t = b4[j];
        bf[4*j+0] = t.x; bf[4*j+1] = t.y; bf[4*j+2] = t.z; bf[4*j+3] = t.w;
    }

    // ---- per-fragment shading + blend precompute ----
    float prob[KFRAG], zinv[KFRAG];
    float cr[KFRAG], cg[KFRAG], cb[KFRAG];
    float zmax = EPSV;

    #pragma unroll
    for (int k = 0; k < KFRAG; k++) {
        int f = fk[k];
        bool m = (f >= 0);
        int fi = m ? f : 0;

        int v0 = faces[3*fi + 0];
        int v1 = faces[3*fi + 1];
        int v2 = faces[3*fi + 2];

        float b0 = bf[3*k + 0], b1 = bf[3*k + 1], b2 = bf[3*k + 2];

        float nx = b0 * vn[3*v0 + 0] + b1 * vn[3*v1 + 0] + b2 * vn[3*v2 + 0];
        float ny = b0 * vn[3*v0 + 1] + b1 * vn[3*v1 + 1] + b2 * vn[3*v2 + 1];
        float nz = b0 * vn[3*v0 + 2] + b1 * vn[3*v1 + 2] + b2 * vn[3*v2 + 2];

        // colors = (n * flip + 1) * 0.5, flip = (1,-1,-1).
        // masked fragments get weight 0 below, so garbage normals are fine.
        cr[k] = (nx + 1.0f) * 0.5f;
        cg[k] = (1.0f - ny) * 0.5f;
        cb[k] = (1.0f - nz) * 0.5f;

        // prob = sigmoid(-d/sigma) * mask = mask / (1 + exp(d/sigma))
        prob[k] = m ? (1.0f / (1.0f + __expf(dk[k] * SIGMA_INV))) : 0.0f;

        // z_inv = (zfar - z)/(zfar - znear) * mask
        zinv[k] = m ? ((ZFAR - zk[k]) * ZRANGE_INV) : 0.0f;
        zmax = fmaxf(zmax, zinv[k]);
    }

    // ---- softmax blend ----
    float delta = fmaxf(__expf((EPSV - zmax) * GAMMA_INV), EPSV);
    float denom = delta;
    float wr = 0.0f, wg = 0.0f, wb = 0.0f;
    float trans = 1.0f;   // prod(1 - prob) = 1 - alpha

    #pragma unroll
    for (int k = 0; k < KFRAG; k++) {
        float w = prob[k] * __expf((zinv[k] - zmax) * GAMMA_INV);
        denom += w;
        wr += w * cr[k];
        wg += w * cg[k];
        wb += w * cb[k];
        trans *= (1.0f - prob[k]);
    }

    float inv = 1.0f / denom;
    float4 o;
    o.x = (wr + delta) * inv;   // bg = (1,1,1): + delta*bg_c
    o.y = (wg + delta) * inv;
    o.z = (wb + delta) * inv;
    o.w = trans;
    ((float4*)out)[p] = o;
}

extern "C" void kernel_launch(void* const* d_in, const int* in_sizes, int n_in,
                              void* d_out, int out_size, void* d_ws, size_t ws_size,
                              hipStream_t stream) {
    const float* vn    = (const float*)d_in[0];  // verts_normals [V,3]
    const float* bary  = (const float*)d_in[1];  // [N,H,W,K,3]
    const float* zbuf  = (const float*)d_in[2];  // [N,H,W,K]
    const float* dists = (const float*)d_in[3];  // [N,H,W,K]
    const int*   faces = (const int*)d_in[4];    // [F,3]
    const int*   p2f   = (const int*)d_in[5];    // [N,H,W,K]
    float* out = (float*)d_out;                  // [N,H,W,4]

    int P = in_sizes[2] / KFRAG;   // N*H*W from zbuf element count
    int block = 256;
    int grid = (P + block - 1) / block;
    soft_phong_kernel<<<grid, block, 0, stream>>>(vn, bary, zbuf, dists, faces,
                                                  p2f, out, P);
}

// Round 2
// 322.518 us; speedup vs baseline: 1.0352x; 1.0352x over previous
//
#include <hip/hip_runtime.h>

// SoftPhongNormalShader, two-phase:
//   Phase 1: materialize per-face interpolation table (3 vertex normals,
//            64-B stride) in d_ws  -> turns 12 random lines/fragment into 1.
//   Phase 2: per-pixel shade + softmax blend; streaming inputs loaded
//            non-temporally so the 6.4 MB face table stays cache-resident.

typedef float f4 __attribute__((ext_vector_type(4)));
typedef int   i4 __attribute__((ext_vector_type(4)));

#define KFRAG 8
#define SIGMA_INV 10000.0f     // 1/1e-4
#define GAMMA_INV 10000.0f     // 1/1e-4
#define ZFAR 100.0f
#define ZRANGE_INV (1.0f / 99.0f)
#define EPSV 1e-10f

__global__ __launch_bounds__(256) void build_face_normals(
    const float* __restrict__ vn,     // [V,3]
    const int*   __restrict__ faces,  // [F,3]
    f4*          __restrict__ fn,     // [F, strideV] f4 rows
    int F, int strideV)
{
    int f = blockIdx.x * blockDim.x + threadIdx.x;
    if (f >= F) return;
    int v0 = faces[3*f + 0];
    int v1 = faces[3*f + 1];
    int v2 = faces[3*f + 2];
    f4 r0 = {vn[3*v0], vn[3*v0+1], vn[3*v0+2], 0.0f};
    f4 r1 = {vn[3*v1], vn[3*v1+1], vn[3*v1+2], 0.0f};
    f4 r2 = {vn[3*v2], vn[3*v2+1], vn[3*v2+2], 0.0f};
    size_t base = (size_t)f * strideV;
    fn[base + 0] = r0;
    fn[base + 1] = r1;
    fn[base + 2] = r2;
}

__global__ __launch_bounds__(256) void soft_phong_kernel(
    const f4*    __restrict__ fn,     // [F, strideV] face-normal table
    const float* __restrict__ bary,   // [P,K,3]
    const float* __restrict__ zbuf,   // [P,K]
    const float* __restrict__ dists,  // [P,K]
    const int*   __restrict__ p2f,    // [P,K]
    float*       __restrict__ out,    // [P,4]
    int P, int strideV)
{
    int p = blockIdx.x * blockDim.x + threadIdx.x;
    if (p >= P) return;

    // ---- streaming loads: contiguous, non-temporal (don't evict fn table) ----
    const i4* pf4 = (const i4*)(p2f + (size_t)p * KFRAG);
    i4 fa = __builtin_nontemporal_load(pf4 + 0);
    i4 fb = __builtin_nontemporal_load(pf4 + 1);
    int fk[KFRAG] = {fa.x, fa.y, fa.z, fa.w, fb.x, fb.y, fb.z, fb.w};

    const f4* z4 = (const f4*)(zbuf + (size_t)p * KFRAG);
    f4 za = __builtin_nontemporal_load(z4 + 0);
    f4 zb = __builtin_nontemporal_load(z4 + 1);
    float zk[KFRAG] = {za.x, za.y, za.z, za.w, zb.x, zb.y, zb.z, zb.w};

    const f4* dd4 = (const f4*)(dists + (size_t)p * KFRAG);
    f4 da = __builtin_nontemporal_load(dd4 + 0);
    f4 db = __builtin_nontemporal_load(dd4 + 1);
    float dk[KFRAG] = {da.x, da.y, da.z, da.w, db.x, db.y, db.z, db.w};

    const f4* b4 = (const f4*)(bary + (size_t)p * KFRAG * 3);
    float bf[24];
    #pragma unroll
    for (int j = 0; j < 6; j++) {
        f4 t = __builtin_nontemporal_load(b4 + j);
        bf[4*j+0] = t.x; bf[4*j+1] = t.y; bf[4*j+2] = t.z; bf[4*j+3] = t.w;
    }

    // ---- issue all face-table gathers up front (1 cache line each) ----
    f4 n0[KFRAG], n1[KFRAG], n2[KFRAG];
    #pragma unroll
    for (int k = 0; k < KFRAG; k++) {
        int fi = fk[k] >= 0 ? fk[k] : 0;
        size_t base = (size_t)fi * strideV;
        n0[k] = fn[base + 0];
        n1[k] = fn[base + 1];
        n2[k] = fn[base + 2];
    }

    // ---- per-fragment shading + blend precompute ----
    float prob[KFRAG], zinv[KFRAG];
    float cr[KFRAG], cg[KFRAG], cb[KFRAG];
    float zmax = EPSV;

    #pragma unroll
    for (int k = 0; k < KFRAG; k++) {
        bool m = (fk[k] >= 0);
        float b0 = bf[3*k + 0], b1 = bf[3*k + 1], b2 = bf[3*k + 2];

        float nx = b0 * n0[k].x + b1 * n1[k].x + b2 * n2[k].x;
        float ny = b0 * n0[k].y + b1 * n1[k].y + b2 * n2[k].y;
        float nz = b0 * n0[k].z + b1 * n1[k].z + b2 * n2[k].z;

        // colors = (n * flip + 1) * 0.5, flip = (1,-1,-1);
        // masked fragments get weight 0 below, garbage normals are harmless
        cr[k] = (nx + 1.0f) * 0.5f;
        cg[k] = (1.0f - ny) * 0.5f;
        cb[k] = (1.0f - nz) * 0.5f;

        prob[k] = m ? (1.0f / (1.0f + __expf(dk[k] * SIGMA_INV))) : 0.0f;
        zinv[k] = m ? ((ZFAR - zk[k]) * ZRANGE_INV) : 0.0f;
        zmax = fmaxf(zmax, zinv[k]);
    }

    // ---- softmax blend ----
    float delta = fmaxf(__expf((EPSV - zmax) * GAMMA_INV), EPSV);
    float denom = delta;
    float wr = 0.0f, wg = 0.0f, wb = 0.0f;
    float trans = 1.0f;

    #pragma unroll
    for (int k = 0; k < KFRAG; k++) {
        float w = prob[k] * __expf((zinv[k] - zmax) * GAMMA_INV);
        denom += w;
        wr += w * cr[k];
        wg += w * cg[k];
        wb += w * cb[k];
        trans *= (1.0f - prob[k]);
    }

    float inv = 1.0f / denom;
    f4 o = {(wr + delta) * inv, (wg + delta) * inv, (wb + delta) * inv, trans};
    __builtin_nontemporal_store(o, (f4*)out + p);
}

extern "C" void kernel_launch(void* const* d_in, const int* in_sizes, int n_in,
                              void* d_out, int out_size, void* d_ws, size_t ws_size,
                              hipStream_t stream) {
    const float* vn    = (const float*)d_in[0];  // verts_normals [V,3]
    const float* bary  = (const float*)d_in[1];  // [N,H,W,K,3]
    const float* zbuf  = (const float*)d_in[2];  // [N,H,W,K]
    const float* dists = (const float*)d_in[3];  // [N,H,W,K]
    const int*   faces = (const int*)d_in[4];    // [F,3]
    const int*   p2f   = (const int*)d_in[5];    // [N,H,W,K]
    float* out = (float*)d_out;                  // [N,H,W,4]

    int P = in_sizes[2] / KFRAG;   // N*H*W
    int F = in_sizes[4] / 3;

    // face-table stride: prefer 64 B (1 line/fragment), fall back to 48 B
    int strideV = (ws_size >= (size_t)F * 64) ? 4 : 3;

    f4* fn = (f4*)d_ws;
    int block = 256;
    build_face_normals<<<(F + block - 1) / block, block, 0, stream>>>(
        vn, faces, fn, F, strideV);
    soft_phong_kernel<<<(P + block - 1) / block, block, 0, stream>>>(
        fn, bary, zbuf, dists, p2f, out, P, strideV);
}

// Round 3
// 275.154 us; speedup vs baseline: 1.2135x; 1.1721x over previous
//
#include <hip/hip_runtime.h>
#include <hip/hip_fp16.h>

// SoftPhongNormalShader, two-phase:
//   Phase 1: per-face fp16 normal table (9 halves, 32-B stride) in d_ws.
//            3.2 MB -> fits per-XCD L2; 1 aligned 32-B chunk per fragment.
//   Phase 2: per-pixel shade + softmax blend. Streaming loads are PLAIN
//            (L3-resident across replays; R2 showed nt loads forced 348 MB
//            of HBM re-fetch and made us latency-bound).

typedef float        f4 __attribute__((ext_vector_type(4)));
typedef int          i4 __attribute__((ext_vector_type(4)));
typedef unsigned int u32;
typedef u32          u4 __attribute__((ext_vector_type(4)));

#define KFRAG 8
#define SIGMA_INV 10000.0f     // 1/1e-4
#define GAMMA_INV 10000.0f     // 1/1e-4
#define ZFAR 100.0f
#define ZRANGE_INV (1.0f / 99.0f)
#define EPSV 1e-10f

union H2U { u32 u; __half2 h; };

__global__ __launch_bounds__(256) void build_face_tab(
    const float* __restrict__ vn,     // [V,3]
    const int*   __restrict__ faces,  // [F,3]
    u32*         __restrict__ tab,    // [F, 8] u32 rows (32 B)
    int F)
{
    int f = blockIdx.x * blockDim.x + threadIdx.x;
    if (f >= F) return;
    int v0 = faces[3*f + 0];
    int v1 = faces[3*f + 1];
    int v2 = faces[3*f + 2];
    float n[9] = {vn[3*v0], vn[3*v0+1], vn[3*v0+2],
                  vn[3*v1], vn[3*v1+1], vn[3*v1+2],
                  vn[3*v2], vn[3*v2+1], vn[3*v2+2]};
    u32* row = tab + (size_t)f * 8;
    H2U a;
    a.h = __floats2half2_rn(n[0], n[1]); u32 w0 = a.u;
    a.h = __floats2half2_rn(n[2], n[3]); u32 w1 = a.u;
    a.h = __floats2half2_rn(n[4], n[5]); u32 w2 = a.u;
    a.h = __floats2half2_rn(n[6], n[7]); u32 w3 = a.u;
    a.h = __floats2half2_rn(n[8], 0.0f); u32 w4 = a.u;
    u4 v = {w0, w1, w2, w3};
    *(u4*)row = v;
    row[4] = w4;
}

__global__ __launch_bounds__(256) void soft_phong_kernel(
    const u32*   __restrict__ tab,    // [F,8] fp16 face-normal rows
    const float* __restrict__ bary,   // [P,K,3]
    const float* __restrict__ zbuf,   // [P,K]
    const float* __restrict__ dists,  // [P,K]
    const int*   __restrict__ p2f,    // [P,K]
    float*       __restrict__ out,    // [P,4]
    int P)
{
    int p = blockIdx.x * blockDim.x + threadIdx.x;
    if (p >= P) return;

    // ---- streaming loads (contiguous, plain -> L2/L3 hits on replay) ----
    const i4* pf4 = (const i4*)(p2f + (size_t)p * KFRAG);
    i4 fa = pf4[0], fb = pf4[1];
    int fk[KFRAG] = {fa.x, fa.y, fa.z, fa.w, fb.x, fb.y, fb.z, fb.w};

    const f4* z4 = (const f4*)(zbuf + (size_t)p * KFRAG);
    f4 za = z4[0], zb = z4[1];
    float zk[KFRAG] = {za.x, za.y, za.z, za.w, zb.x, zb.y, zb.z, zb.w};

    const f4* dd4 = (const f4*)(dists + (size_t)p * KFRAG);
    f4 da = dd4[0], db = dd4[1];
    float dk[KFRAG] = {da.x, da.y, da.z, da.w, db.x, db.y, db.z, db.w};

    const f4* b4 = (const f4*)(bary + (size_t)p * KFRAG * 3);
    float bf[24];
    #pragma unroll
    for (int j = 0; j < 6; j++) {
        f4 t = b4[j];
        bf[4*j+0] = t.x; bf[4*j+1] = t.y; bf[4*j+2] = t.z; bf[4*j+3] = t.w;
    }

    // ---- face-table gathers: 20 B in one aligned 32-B chunk each ----
    u4  ga[KFRAG];
    u32 gb[KFRAG];
    #pragma unroll
    for (int k = 0; k < KFRAG; k++) {
        int fi = fk[k] >= 0 ? fk[k] : 0;
        const u32* row = tab + (size_t)fi * 8;
        ga[k] = *(const u4*)row;
        gb[k] = row[4];
    }

    // ---- per-fragment shading + blend precompute ----
    float prob[KFRAG], zinv[KFRAG];
    float cr[KFRAG], cg[KFRAG], cb[KFRAG];
    float zmax = EPSV;

    #pragma unroll
    for (int k = 0; k < KFRAG; k++) {
        bool m = (fk[k] >= 0);
        float b0 = bf[3*k + 0], b1 = bf[3*k + 1], b2 = bf[3*k + 2];

        H2U u;
        u.u = ga[k].x; float2 f01 = __half22float2(u.h);  // n0x n0y
        u.u = ga[k].y; float2 f23 = __half22float2(u.h);  // n0z n1x
        u.u = ga[k].z; float2 f45 = __half22float2(u.h);  // n1y n1z
        u.u = ga[k].w; float2 f67 = __half22float2(u.h);  // n2x n2y
        u.u = gb[k];   float2 f8x = __half22float2(u.h);  // n2z --

        float nx = b0 * f01.x + b1 * f23.y + b2 * f67.x;
        float ny = b0 * f01.y + b1 * f45.x + b2 * f67.y;
        float nz = b0 * f23.x + b1 * f45.y + b2 * f8x.x;

        // colors = (n*flip + 1)*0.5, flip=(1,-1,-1); masked frags get w=0
        cr[k] = (nx + 1.0f) * 0.5f;
        cg[k] = (1.0f - ny) * 0.5f;
        cb[k] = (1.0f - nz) * 0.5f;

        prob[k] = m ? (1.0f / (1.0f + __expf(dk[k] * SIGMA_INV))) : 0.0f;
        zinv[k] = m ? ((ZFAR - zk[k]) * ZRANGE_INV) : 0.0f;
        zmax = fmaxf(zmax, zinv[k]);
    }

    // ---- softmax blend ----
    float delta = fmaxf(__expf((EPSV - zmax) * GAMMA_INV), EPSV);
    float denom = delta;
    float wr = 0.0f, wg = 0.0f, wb = 0.0f;
    float trans = 1.0f;

    #pragma unroll
    for (int k = 0; k < KFRAG; k++) {
        float w = prob[k] * __expf((zinv[k] - zmax) * GAMMA_INV);
        denom += w;
        wr += w * cr[k];
        wg += w * cg[k];
        wb += w * cb[k];
        trans *= (1.0f - prob[k]);
    }

    float inv = 1.0f / denom;
    f4 o = {(wr + delta) * inv, (wg + delta) * inv, (wb + delta) * inv, trans};
    __builtin_nontemporal_store(o, (f4*)out + p);   // keep out of L2/L3
}

extern "C" void kernel_launch(void* const* d_in, const int* in_sizes, int n_in,
                              void* d_out, int out_size, void* d_ws, size_t ws_size,
                              hipStream_t stream) {
    const float* vn    = (const float*)d_in[0];  // verts_normals [V,3]
    const float* bary  = (const float*)d_in[1];  // [N,H,W,K,3]
    const float* zbuf  = (const float*)d_in[2];  // [N,H,W,K]
    const float* dists = (const float*)d_in[3];  // [N,H,W,K]
    const int*   faces = (const int*)d_in[4];    // [F,3]
    const int*   p2f   = (const int*)d_in[5];    // [N,H,W,K]
    float* out = (float*)d_out;                  // [N,H,W,4]

    int P = in_sizes[2] / KFRAG;   // N*H*W
    int F = in_sizes[4] / 3;

    u32* tab = (u32*)d_ws;         // F * 32 B = 3.2 MB
    int block = 256;
    build_face_tab<<<(F + block - 1) / block, block, 0, stream>>>(
        vn, faces, tab, F);
    soft_phong_kernel<<<(P + block - 1) / block, block, 0, stream>>>(
        tab, bary, zbuf, dists, p2f, out, P);
}

// Round 4
// 242.679 us; speedup vs baseline: 1.3758x; 1.1338x over previous
//
#include <hip/hip_runtime.h>

// SoftPhongNormalShader, two-phase:
//   Phase 1: per-face table, ONE 16-B row per face: 3 vertex normals packed
//            as 3x10-bit unorm codes per dword ({n0,n1,n2,0}). 1.6 MB ->
//            L2-resident; exactly ONE divergent 16-B load per fragment
//            (R3 was L1-miss-transaction-bound at 16 gather instrs/thread).
//   Phase 2: per-pixel shade + softmax blend. Colors are affine in n and
//            sum(bary)=1, so we interpolate the unorm codes directly.

typedef float        f4 __attribute__((ext_vector_type(4)));
typedef int          i4 __attribute__((ext_vector_type(4)));
typedef unsigned int u32;
typedef u32          u4 __attribute__((ext_vector_type(4)));

#define KFRAG 8
#define SIGMA_INV 10000.0f     // 1/1e-4
#define GAMMA_INV 10000.0f     // 1/1e-4
#define ZFAR 100.0f
#define ZRANGE_INV (1.0f / 99.0f)
#define EPSV 1e-10f
#define QSCALE 1023.0f
#define QINV (1.0f / 1023.0f)

__device__ __forceinline__ u32 pack10(float x, float y, float z) {
    // map [-1,1] -> [0,1023] unorm code; code/1023 == (n+1)/2
    u32 qx = (u32)__float2int_rn(__saturatef(x * 0.5f + 0.5f) * QSCALE);
    u32 qy = (u32)__float2int_rn(__saturatef(y * 0.5f + 0.5f) * QSCALE);
    u32 qz = (u32)__float2int_rn(__saturatef(z * 0.5f + 0.5f) * QSCALE);
    return qx | (qy << 10) | (qz << 20);
}

__global__ __launch_bounds__(256) void build_face_tab(
    const float* __restrict__ vn,     // [V,3]
    const int*   __restrict__ faces,  // [F,3]
    u4*          __restrict__ tab,    // [F] 16-B rows
    int F)
{
    int f = blockIdx.x * blockDim.x + threadIdx.x;
    if (f >= F) return;
    int v0 = faces[3*f + 0];
    int v1 = faces[3*f + 1];
    int v2 = faces[3*f + 2];
    u4 row;
    row.x = pack10(vn[3*v0], vn[3*v0+1], vn[3*v0+2]);
    row.y = pack10(vn[3*v1], vn[3*v1+1], vn[3*v1+2]);
    row.z = pack10(vn[3*v2], vn[3*v2+1], vn[3*v2+2]);
    row.w = 0;
    tab[f] = row;
}

__global__ __launch_bounds__(256) void soft_phong_kernel(
    const u4*    __restrict__ tab,    // [F] packed face rows
    const float* __restrict__ bary,   // [P,K,3]
    const float* __restrict__ zbuf,   // [P,K]
    const float* __restrict__ dists,  // [P,K]
    const int*   __restrict__ p2f,    // [P,K]
    float*       __restrict__ out,    // [P,4]
    int P)
{
    int p = blockIdx.x * blockDim.x + threadIdx.x;
    if (p >= P) return;

    // ---- streaming loads (contiguous; L2/L3-resident across replays) ----
    const i4* pf4 = (const i4*)(p2f + (size_t)p * KFRAG);
    i4 fa = pf4[0], fb = pf4[1];
    int fk[KFRAG] = {fa.x, fa.y, fa.z, fa.w, fb.x, fb.y, fb.z, fb.w};

    const f4* z4 = (const f4*)(zbuf + (size_t)p * KFRAG);
    f4 za = z4[0], zb = z4[1];
    float zk[KFRAG] = {za.x, za.y, za.z, za.w, zb.x, zb.y, zb.z, zb.w};

    const f4* dd4 = (const f4*)(dists + (size_t)p * KFRAG);
    f4 da = dd4[0], db = dd4[1];
    float dk[KFRAG] = {da.x, da.y, da.z, da.w, db.x, db.y, db.z, db.w};

    const f4* b4 = (const f4*)(bary + (size_t)p * KFRAG * 3);
    float bf[24];
    #pragma unroll
    for (int j = 0; j < 6; j++) {
        f4 t = b4[j];
        bf[4*j+0] = t.x; bf[4*j+1] = t.y; bf[4*j+2] = t.z; bf[4*j+3] = t.w;
    }

    // ---- face-table gathers: exactly one 16-B load per fragment ----
    u4 ga[KFRAG];
    #pragma unroll
    for (int k = 0; k < KFRAG; k++) {
        int fi = fk[k] >= 0 ? fk[k] : 0;
        ga[k] = tab[fi];
    }

    // ---- per-fragment shading + blend precompute ----
    float prob[KFRAG], zinv[KFRAG];
    float cr[KFRAG], cg[KFRAG], cb[KFRAG];
    float zmax = EPSV;

    #pragma unroll
    for (int k = 0; k < KFRAG; k++) {
        bool m = (fk[k] >= 0);
        float b0 = bf[3*k + 0], b1 = bf[3*k + 1], b2 = bf[3*k + 2];

        u32 w0 = ga[k].x, w1 = ga[k].y, w2 = ga[k].z;
        // code/1023 = (n+1)/2; since b0+b1+b2 = 1:
        //   cr = (nx+1)/2        = (b0 q0x + b1 q1x + b2 q2x)/1023
        //   cg = (1-ny)/2 = 1 - (ny+1)/2 = 1 - (Σ b qy)/1023, same for cb
        float sx = b0 * (float)(w0 & 1023u)
                 + b1 * (float)(w1 & 1023u)
                 + b2 * (float)(w2 & 1023u);
        float sy = b0 * (float)((w0 >> 10) & 1023u)
                 + b1 * (float)((w1 >> 10) & 1023u)
                 + b2 * (float)((w2 >> 10) & 1023u);
        float sz = b0 * (float)(w0 >> 20)
                 + b1 * (float)(w1 >> 20)
                 + b2 * (float)(w2 >> 20);
        cr[k] = sx * QINV;
        cg[k] = 1.0f - sy * QINV;
        cb[k] = 1.0f - sz * QINV;

        prob[k] = m ? (1.0f / (1.0f + __expf(dk[k] * SIGMA_INV))) : 0.0f;
        zinv[k] = m ? ((ZFAR - zk[k]) * ZRANGE_INV) : 0.0f;
        zmax = fmaxf(zmax, zinv[k]);
    }

    // ---- softmax blend ----
    float delta = fmaxf(__expf((EPSV - zmax) * GAMMA_INV), EPSV);
    float denom = delta;
    float wr = 0.0f, wg = 0.0f, wb = 0.0f;
    float trans = 1.0f;

    #pragma unroll
    for (int k = 0; k < KFRAG; k++) {
        float w = prob[k] * __expf((zinv[k] - zmax) * GAMMA_INV);
        denom += w;
        wr += w * cr[k];
        wg += w * cg[k];
        wb += w * cb[k];
        trans *= (1.0f - prob[k]);
    }

    float inv = 1.0f / denom;
    f4 o = {(wr + delta) * inv, (wg + delta) * inv, (wb + delta) * inv, trans};
    __builtin_nontemporal_store(o, (f4*)out + p);   // write-once, keep out of caches
}

extern "C" void kernel_launch(void* const* d_in, const int* in_sizes, int n_in,
                              void* d_out, int out_size, void* d_ws, size_t ws_size,
                              hipStream_t stream) {
    const float* vn    = (const float*)d_in[0];  // verts_normals [V,3]
    const float* bary  = (const float*)d_in[1];  // [N,H,W,K,3]
    const float* zbuf  = (const float*)d_in[2];  // [N,H,W,K]
    const float* dists = (const float*)d_in[3];  // [N,H,W,K]
    const int*   faces = (const int*)d_in[4];    // [F,3]
    const int*   p2f   = (const int*)d_in[5];    // [N,H,W,K]
    float* out = (float*)d_out;                  // [N,H,W,4]

    int P = in_sizes[2] / KFRAG;   // N*H*W
    int F = in_sizes[4] / 3;

    u4* tab = (u4*)d_ws;           // F * 16 B = 1.6 MB
    int block = 256;
    build_face_tab<<<(F + block - 1) / block, block, 0, stream>>>(
        vn, faces, tab, F);
    soft_phong_kernel<<<(P + block - 1) / block, block, 0, stream>>>(
        tab, bary, zbuf, dists, p2f, out, P);
}